// Round 3
// baseline (268.986 us; speedup 1.0000x reference)
//
#include <hip/hip_runtime.h>
#include <hip/hip_bf16.h>

typedef __bf16 bf16x8 __attribute__((ext_vector_type(8)));
typedef float  f32x4  __attribute__((ext_vector_type(4)));

#define LOG2E 1.4426950408889634f
#define LN2   0.6931471805599453f

__device__ __forceinline__ float rcp_(float x){
#if __has_builtin(__builtin_amdgcn_rcpf)
  return __builtin_amdgcn_rcpf(x);
#else
  return 1.0f / x;
#endif
}
__device__ __forceinline__ float ex2_(float x){
#if __has_builtin(__builtin_amdgcn_exp2f)
  return __builtin_amdgcn_exp2f(x);
#else
  return exp2f(x);
#endif
}
__device__ __forceinline__ float lg2_(float x){
#if __has_builtin(__builtin_amdgcn_logf)
  return __builtin_amdgcn_logf(x);
#else
  return log2f(x);
#endif
}
// pre-scaled activations: inputs already multiplied by -LOG2E (sigmoid) / 2*LOG2E (tanh)
__device__ __forceinline__ float sigp_(float xp){ return rcp_(1.0f + ex2_(xp)); }
__device__ __forceinline__ float tanp_(float gp){ return 1.0f - 2.0f*rcp_(1.0f + ex2_(gp)); }

struct LstmArgs {
  const float* Wih[4]; const float* Whh[4];
  const float* bih[4]; const float* bhh[4];
  const float* h0[4];  const float* c0[4];
};

// ---------------------------------------------------------------------------
// Kernel A: 4 directions x 64 batch-blocks of 32 rows. Weights in registers as
// MFMA B-fragments (pre-scaled, vectorized float4/float2 loads). Whole x-tile
// staged to LDS once via float4 loads; 28-step loop touches no global memory.
// ---------------------------------------------------------------------------
__global__ __launch_bounds__(256, 1) void lstm4_kernel(const float* __restrict__ x,
                                                       LstmArgs args,
                                                       float* __restrict__ featT)
{
  const int dir = blockIdx.x >> 6;          // 0=lr_f 1=lr_b 2=ud_f 3=ud_b
  const int b0  = (blockIdx.x & 63) * 32;
  const int tid = threadIdx.x;
  const int w   = tid >> 6;                 // wave 0..3
  const int l   = tid & 63;
  const int lc  = l & 15;
  const int lr4 = l >> 4;

  const float* __restrict__ Wih = args.Wih[dir];
  const float* __restrict__ Whh = args.Whh[dir];
  const float* __restrict__ bih = args.bih[dir];
  const float* __restrict__ bhh = args.bhh[dir];
  const float* __restrict__ h0  = args.h0[dir];
  const float* __restrict__ c0  = args.c0[dir];
  const int rev = dir & 1;
  const bool lrdir = (dir < 2);

  __shared__ __align__(16) __bf16 hcat[32 * 168];        // 10.5 KiB
  __shared__ __align__(16) __bf16 xstage[28 * 32 * 40];  // 70 KiB

  // ---- B fragments (weights) into registers, pre-scaled, vectorized -------
  bf16x8 bfr[8][5];
  float  bias[8];
#pragma unroll
  for (int tl = 0; tl < 8; ++tl){
    const int tg = 2*w + (tl & 1) + 8*(tl >> 1);
    const int g  = tg*16 + lc;
    const float sc = ((tl >> 1) == 2) ? 2.0f*LOG2E : -LOG2E;
    bias[tl] = (bih[g] + bhh[g]) * sc;
#pragma unroll
    for (int kk = 0; kk < 4; ++kk){
      const float4* p = (const float4*)(Whh + g*128 + kk*32 + lr4*8);
      const float4 a0 = p[0], a1 = p[1];
      bf16x8 v;
      v[0]=(__bf16)(a0.x*sc); v[1]=(__bf16)(a0.y*sc); v[2]=(__bf16)(a0.z*sc); v[3]=(__bf16)(a0.w*sc);
      v[4]=(__bf16)(a1.x*sc); v[5]=(__bf16)(a1.y*sc); v[6]=(__bf16)(a1.z*sc); v[7]=(__bf16)(a1.w*sc);
      bfr[tl][kk] = v;
    }
    bf16x8 v;
    if (lr4 < 3){                                  // x part, K=128..151
      const float2* p = (const float2*)(Wih + g*28 + lr4*8);
      const float2 a0=p[0], a1=p[1], a2=p[2], a3=p[3];
      v[0]=(__bf16)(a0.x*sc); v[1]=(__bf16)(a0.y*sc); v[2]=(__bf16)(a1.x*sc); v[3]=(__bf16)(a1.y*sc);
      v[4]=(__bf16)(a2.x*sc); v[5]=(__bf16)(a2.y*sc); v[6]=(__bf16)(a3.x*sc); v[7]=(__bf16)(a3.y*sc);
    } else {                                       // K=152..159: cols 24..27 real
      const float2* p = (const float2*)(Wih + g*28 + 24);
      const float2 a0=p[0], a1=p[1];
      v[0]=(__bf16)(a0.x*sc); v[1]=(__bf16)(a0.y*sc); v[2]=(__bf16)(a1.x*sc); v[3]=(__bf16)(a1.y*sc);
      v[4]=(__bf16)0.0f; v[5]=(__bf16)0.0f; v[6]=(__bf16)0.0f; v[7]=(__bf16)0.0f;
    }
    bfr[tl][4] = v;
  }

  // ---- stage whole x tile once, float4 global loads ------------------------
  for (int idx = tid; idx < 32*196; idx += 256){   // 196 = 28*7 float4 per row
    const int row = idx / 196;
    const int rem = idx - row*196;
    if (lrdir){
      const int t = rem / 7, jg = rem - 7*t;
      const float4 v = *(const float4*)&x[(b0+row)*784 + t*28 + jg*4];
      __bf16* dst = &xstage[(t*32 + row)*40 + jg*4];
      dst[0]=(__bf16)v.x; dst[1]=(__bf16)v.y; dst[2]=(__bf16)v.z; dst[3]=(__bf16)v.w;
    } else {
      const int j = rem / 7, tg = rem - 7*j;
      const float4 v = *(const float4*)&x[(b0+row)*784 + j*28 + tg*4];
      xstage[((tg*4+0)*32 + row)*40 + j] = (__bf16)v.x;
      xstage[((tg*4+1)*32 + row)*40 + j] = (__bf16)v.y;
      xstage[((tg*4+2)*32 + row)*40 + j] = (__bf16)v.z;
      xstage[((tg*4+3)*32 + row)*40 + j] = (__bf16)v.w;
    }
  }
  for (int idx = tid; idx < 28*32; idx += 256){    // zero K-pad cols 28..31
    const int t = idx >> 5, row = idx & 31;
    __bf16* p = &xstage[(t*32 + row)*40 + 28];
    p[0] = p[1] = p[2] = p[3] = (__bf16)0.0f;
  }

  // ---- initial state -------------------------------------------------------
  float cst[2][2][4];
  float hfin[2][2][4];
#pragma unroll
  for (int m = 0; m < 2; ++m)
#pragma unroll
  for (int p = 0; p < 2; ++p)
#pragma unroll
  for (int r = 0; r < 4; ++r){
    const int row = 16*m + 4*lr4 + r;
    const int col = 32*w + 16*p + lc;
    cst[m][p][r] = c0[(b0+row)*128 + col];
    hcat[row*168 + col] = (__bf16)h0[(b0+row)*128 + col];
    hfin[m][p][r] = 0.0f;
  }

  // ---- 28 sequential steps -------------------------------------------------
  for (int s = 0; s < 28; ++s){
    const int t = rev ? (27 - s) : s;
    __syncthreads();

    f32x4 acc[2][8];
#pragma unroll
    for (int m = 0; m < 2; ++m)
#pragma unroll
    for (int tl = 0; tl < 8; ++tl){
      f32x4 bv = {bias[tl], bias[tl], bias[tl], bias[tl]};
      acc[m][tl] = bv;
    }

#pragma unroll
    for (int m = 0; m < 2; ++m){
#pragma unroll
      for (int kk = 0; kk < 5; ++kk){
        const bf16x8 a = (kk < 4)
          ? *(const bf16x8*)&hcat[(16*m + lc)*168 + kk*32 + lr4*8]
          : *(const bf16x8*)&xstage[(t*32 + 16*m + lc)*40 + lr4*8];
#pragma unroll
        for (int tl = 0; tl < 8; ++tl)
          acc[m][tl] = __builtin_amdgcn_mfma_f32_16x16x32_bf16(a, bfr[tl][kk], acc[m][tl], 0, 0, 0);
      }
    }
    __syncthreads();

#pragma unroll
    for (int m = 0; m < 2; ++m)
#pragma unroll
    for (int p = 0; p < 2; ++p)
#pragma unroll
    for (int r = 0; r < 4; ++r){
      const float iv = acc[m][0+p][r];
      const float fv = acc[m][2+p][r];
      const float gv = acc[m][4+p][r];
      const float ov = acc[m][6+p][r];
      const float cc = sigp_(fv)*cst[m][p][r] + sigp_(iv)*tanp_(gv);
      cst[m][p][r] = cc;
      const float hv = sigp_(ov)*tanp_(2.0f*LOG2E*cc);
      hfin[m][p][r] = hv;
      const int row = 16*m + 4*lr4 + r;
      const int col = 32*w + 16*p + lc;
      hcat[row*168 + col] = (__bf16)hv;
    }
  }

  // ---- final h -> featT[512][2048] ----------------------------------------
#pragma unroll
  for (int m = 0; m < 2; ++m)
#pragma unroll
  for (int p = 0; p < 2; ++p){
    const int col = 32*w + 16*p + lc;
    f32x4 v = {hfin[m][p][0], hfin[m][p][1], hfin[m][p][2], hfin[m][p][3]};
    *(f32x4*)&featT[(dir*128 + col)*2048 + b0 + 16*m + 4*lr4] = v;
  }
}

// ---------------------------------------------------------------------------
// Kernel B: fc LSTM via MFMA. One 64-lane wave owns 16 batch elements.
// Gate rows ordered row = 4*unit + gate  ->  C-fragment regs r=0..3 of lane l
// are i,f,g,o of unit (mt*4 + l>>4) for batch (l&15): update is lane-local.
// A (weights) = 3 loop-invariant register fragments (48x32, units>=10 and
// k>=10 zero). B (h) read per step as one ds_read_b128 from a 1 KiB LDS tile.
// ---------------------------------------------------------------------------
__global__ __launch_bounds__(64, 1) void fc_lstm_mfma(const float* __restrict__ featT,
                                                      const float* __restrict__ Wih,
                                                      const float* __restrict__ Whh,
                                                      const float* __restrict__ bih,
                                                      const float* __restrict__ bhh,
                                                      const float* __restrict__ h0,
                                                      const float* __restrict__ c0,
                                                      float* __restrict__ out)
{
  const int l = threadIdx.x;
  const int b = l & 15;                 // batch column
  const int grp = l >> 4;               // lane group
  const int bbase = blockIdx.x * 16;

  __shared__ __align__(16) __bf16 hl[16*32];   // h[batch][unit(0..31)], bf16

  // ---- A fragments (weights) + C-init coefficients -------------------------
  bf16x8 afr[3];
  float bias_r[3][4], wih_r[3][4];
#pragma unroll
  for (int mt = 0; mt < 3; ++mt){
    const int row = mt*16 + b;          // gate-row index (here b plays l&15 role)
    const int m = row >> 2;             // unit
    const int g = row & 3;              // gate: 0=i 1=f 2=g 3=o
    const float sc = (g==2) ? 2.0f*LOG2E : -LOG2E;
    bf16x8 v;
#pragma unroll
    for (int j = 0; j < 8; ++j){
      const int k = grp*8 + j;
      const float wv = (m < 10 && k < 10) ? Whh[(g*10 + m)*10 + k] * sc : 0.0f;
      v[j] = (__bf16)wv;
    }
    afr[mt] = v;
    const int mm = mt*4 + grp;          // unit this lane's C-regs hold
#pragma unroll
    for (int r = 0; r < 4; ++r){
      if (mm < 10){
        const float scr = (r==2) ? 2.0f*LOG2E : -LOG2E;
        bias_r[mt][r] = (bih[r*10+mm] + bhh[r*10+mm]) * scr;
        wih_r[mt][r]  = Wih[r*10+mm] * scr;
      } else { bias_r[mt][r] = 0.0f; wih_r[mt][r] = 0.0f; }
    }
  }

  // ---- state + LDS init ----------------------------------------------------
  float c_st[3], h_st[3];
#pragma unroll
  for (int u = 0; u < 8; ++u) hl[l*8 + u] = (__bf16)0.0f;   // covers all 512
#pragma unroll
  for (int mt = 0; mt < 3; ++mt){
    const int mm = mt*4 + grp;
    c_st[mt] = (mm < 10) ? c0[(bbase+b)*10 + mm] : 0.0f;
    h_st[mt] = (mm < 10) ? h0[(bbase+b)*10 + mm] : 0.0f;
    if (mm < 10) hl[b*32 + mm] = (__bf16)h_st[mt];          // after zeros: wave-ordered
  }

  // ---- 512 sequential steps ------------------------------------------------
  float xt = featT[bbase + b];
  for (int t = 0; t < 512; ++t){
    asm volatile("s_waitcnt lgkmcnt(0)" ::: "memory");
    __builtin_amdgcn_sched_barrier(0);
    const bf16x8 bfrag = *(const bf16x8*)&hl[b*32 + grp*8];

    float xt_n = 0.0f;
    if (t < 511) xt_n = featT[(t+1)*2048 + bbase + b];      // prefetch

    f32x4 acc[3];
#pragma unroll
    for (int mt = 0; mt < 3; ++mt){
#pragma unroll
      for (int r = 0; r < 4; ++r) acc[mt][r] = bias_r[mt][r] + wih_r[mt][r]*xt;
      acc[mt] = __builtin_amdgcn_mfma_f32_16x16x32_bf16(afr[mt], bfrag, acc[mt], 0, 0, 0);
    }

#pragma unroll
    for (int mt = 0; mt < 3; ++mt){
      const float cc = sigp_(acc[mt][1])*c_st[mt] + sigp_(acc[mt][0])*tanp_(acc[mt][2]);
      c_st[mt] = cc;
      h_st[mt] = sigp_(acc[mt][3])*tanp_(2.0f*LOG2E*cc);
    }
    xt = xt_n;

#pragma unroll
    for (int mt = 0; mt < 3; ++mt){
      const int mm = mt*4 + grp;
      if (mm < 10) hl[b*32 + mm] = (__bf16)h_st[mt];
    }
  }

  // ---- log-softmax over units 0..9 of each batch column --------------------
  float pm = -3.0e38f;
#pragma unroll
  for (int mt = 0; mt < 3; ++mt){ const int mm = mt*4+grp; if (mm < 10) pm = fmaxf(pm, h_st[mt]); }
  pm = fmaxf(pm, __shfl_xor(pm, 16, 64));
  pm = fmaxf(pm, __shfl_xor(pm, 32, 64));
  float es = 0.0f;
#pragma unroll
  for (int mt = 0; mt < 3; ++mt){ const int mm = mt*4+grp; if (mm < 10) es += ex2_(LOG2E*(h_st[mt]-pm)); }
  es += __shfl_xor(es, 16, 64);
  es += __shfl_xor(es, 32, 64);
  const float lse = LN2 * lg2_(es);
#pragma unroll
  for (int mt = 0; mt < 3; ++mt){
    const int mm = mt*4 + grp;
    if (mm < 10) out[(bbase+b)*10 + mm] = h_st[mt] - pm - lse;
  }
}

extern "C" void kernel_launch(void* const* d_in, const int* in_sizes, int n_in,
                              void* d_out, int out_size, void* d_ws, size_t ws_size,
                              hipStream_t stream)
{
  const float* x = (const float*)d_in[0];
  LstmArgs a;
  const int base[4] = {1, 5, 9, 13};   // lr_f, lr_b, ud_f, ud_b
  for (int d = 0; d < 4; ++d){
    a.Wih[d] = (const float*)d_in[base[d] + 0];
    a.Whh[d] = (const float*)d_in[base[d] + 1];
    a.bih[d] = (const float*)d_in[base[d] + 2];
    a.bhh[d] = (const float*)d_in[base[d] + 3];
  }
  const float* h0lr = (const float*)d_in[21];
  const float* c0lr = (const float*)d_in[22];
  const float* h0ud = (const float*)d_in[23];
  const float* c0ud = (const float*)d_in[24];
  a.h0[0] = h0lr;               a.c0[0] = c0lr;
  a.h0[1] = h0lr + 2048*128;    a.c0[1] = c0lr + 2048*128;
  a.h0[2] = h0ud;               a.c0[2] = c0ud;
  a.h0[3] = h0ud + 2048*128;    a.c0[3] = c0ud + 2048*128;

  float* featT = (float*)d_ws;   // [512][2048] f32 = 4 MiB

  lstm4_kernel<<<256, 256, 0, stream>>>(x, a, featT);
  fc_lstm_mfma<<<128, 64, 0, stream>>>(featT,
      (const float*)d_in[17], (const float*)d_in[18],
      (const float*)d_in[19], (const float*)d_in[20],
      (const float*)d_in[25], (const float*)d_in[26],
      (float*)d_out);
}